// Round 3
// baseline (1175.824 us; speedup 1.0000x reference)
//
#include <hip/hip_runtime.h>
#include <cstddef>
#include <cstdint>

#define DM   128
#define NH   8
#define DP   16
#define SEQ  2048
#define BB   4
#define CK   128
#define NCH  (SEQ / CK)   // 16

__device__ __forceinline__ float dot16(const float4 a[4], const float4 b[4]) {
  float s = 0.f;
#pragma unroll
  for (int i = 0; i < 4; ++i)
    s += a[i].x * b[i].x + a[i].y * b[i].y + a[i].z * b[i].z + a[i].w * b[i].w;
  return s;
}

// out[64 rows @ row0][128] = X @ W[128][128] + bias
// headsplit=1: store to [B,H,S,16] layout; else row-major [M,128]
__device__ __forceinline__ void gemm128_body(
    const float* __restrict__ X, const float* __restrict__ W,
    const float* __restrict__ bias, float* __restrict__ out,
    int row0, int headsplit)
{
  __shared__ float xs[64][DM];   // 32 KB
  const int t = threadIdx.x;
  {
    const float4* Xv = (const float4*)(X + (size_t)row0 * DM);
    float4* xsv = (float4*)&xs[0][0];
#pragma unroll
    for (int i = 0; i < 8; ++i) xsv[t + i * 256] = Xv[t + i * 256];
  }
  __syncthreads();
  const int cg = t & 31;   // cols cg*4 .. cg*4+3
  const int rg = t >> 5;   // rows rg*8 .. rg*8+7
  float acc[8][4];
#pragma unroll
  for (int i = 0; i < 8; ++i)
#pragma unroll
    for (int j = 0; j < 4; ++j) acc[i][j] = 0.f;

  for (int k = 0; k < DM; k += 4) {
    float4 w0 = *(const float4*)(W + (size_t)(k + 0) * DM + cg * 4);
    float4 w1 = *(const float4*)(W + (size_t)(k + 1) * DM + cg * 4);
    float4 w2 = *(const float4*)(W + (size_t)(k + 2) * DM + cg * 4);
    float4 w3 = *(const float4*)(W + (size_t)(k + 3) * DM + cg * 4);
#pragma unroll
    for (int i = 0; i < 8; ++i) {
      float4 xv = *(const float4*)(&xs[rg * 8 + i][k]);
      acc[i][0] += xv.x * w0.x + xv.y * w1.x + xv.z * w2.x + xv.w * w3.x;
      acc[i][1] += xv.x * w0.y + xv.y * w1.y + xv.z * w2.y + xv.w * w3.y;
      acc[i][2] += xv.x * w0.z + xv.y * w1.z + xv.z * w2.z + xv.w * w3.z;
      acc[i][3] += xv.x * w0.w + xv.y * w1.w + xv.z * w2.w + xv.w * w3.w;
    }
  }
  float4 bv = *(const float4*)(bias + cg * 4);
#pragma unroll
  for (int i = 0; i < 8; ++i) {
    int row = row0 + rg * 8 + i;
    float4 o;
    o.x = acc[i][0] + bv.x; o.y = acc[i][1] + bv.y;
    o.z = acc[i][2] + bv.z; o.w = acc[i][3] + bv.w;
    if (headsplit) {
      int b = row >> 11, s = row & (SEQ - 1);
      int col = cg * 4;
      int h = col >> 4, d = col & 15;
      *(float4*)(out + (((size_t)(b * NH + h) * SEQ + s) * DP + d)) = o;
    } else {
      *(float4*)(out + (size_t)row * DM + cg * 4) = o;
    }
  }
}

__global__ __launch_bounds__(256) void proj_kernel(
    const float* __restrict__ q, const float* __restrict__ k,
    const float* __restrict__ v, const float* __restrict__ W,
    const float* __restrict__ bias, float* __restrict__ ws)
{
  const float* X = (blockIdx.y == 0) ? q : (blockIdx.y == 1) ? k : v;
  float* out = ws + (size_t)blockIdx.y * ((size_t)BB * SEQ * DM);
  gemm128_body(X, W, bias, out, blockIdx.x * 64, 1);
}

__global__ __launch_bounds__(256) void dense_kernel(
    const float* __restrict__ ctx, const float* __restrict__ W,
    const float* __restrict__ bias, float* __restrict__ out)
{
  // buggy reshape [B,H,S,dp]->[B,S,128] without head transpose == flat [8192][128]
  gemm128_body(ctx, W, bias, out, blockIdx.x * 64, 0);
}

// 8 q-rows per block (4 waves x 2 rows, rows+logits in registers).
// K/V staged in double-buffered LDS chunks of 128 keys, padded to 20 floats/row
// (b128 reads: 8 lanes cover all 32 banks -> conflict-free, LDS/VALU balanced).
// One barrier per chunk; next chunk's global loads issue right after the
// barrier so their L2 latency hides under the current chunk's FMAs.
// attn matrix (512 MiB, never re-read) stored non-temporally to keep K/V
// panels resident in L2 across the 256 blocks that share them.
__global__ __launch_bounds__(256) void attn_kernel(
    const float* __restrict__ qh, const float* __restrict__ kh,
    const float* __restrict__ vh, const float* __restrict__ mask,
    float* __restrict__ attn, float* __restrict__ ctx)
{
  __shared__ float kch[2][CK * 20];   // 20 KB ping-pong
  float4* kb0 = (float4*)kch[0];
  float4* kb1 = (float4*)kch[1];

  const int t = threadIdx.x;
  const int lane = t & 63;
  const int w = t >> 6;            // wave 0..3
  const int bh = blockIdx.x >> 8;  // 0..31  (consecutive blocks share K/V in L2)
  const int qt = blockIdx.x & 255;
  const int b = bh >> 3;
  const int r0 = qt * 8 + w * 2;   // wave's first q row

  const float4* K4 = (const float4*)(kh + (size_t)bh * SEQ * DP);
  const float4* V4 = (const float4*)(vh + (size_t)bh * SEQ * DP);
  const float* mp = mask + (size_t)b * SEQ;

  const int i0 = t, i1 = t + 256;                 // 512 float4 per chunk
  const int s0lds = (i0 >> 2) * 5 + (i0 & 3);     // padded LDS slots
  const int s1lds = (i1 >> 2) * 5 + (i1 & 3);

  float4 qa[4], qb[4];
  {
    const float4* Q4 = (const float4*)(qh + ((size_t)bh * SEQ + r0) * DP);
#pragma unroll
    for (int s = 0; s < 4; ++s) { qa[s] = Q4[s]; qb[s] = Q4[4 + s]; }
  }

  float p0[2 * NCH], p1[2 * NCH];   // raw logits -> exp values, in registers

  // ---- QK^T (double-buffered) ----
  { // prologue: chunk 0 -> buf0
    float4 g0 = K4[i0], g1 = K4[i1];
    kb0[s0lds] = g0; kb0[s1lds] = g1;
  }
#pragma unroll
  for (int cc = 0; cc < NCH; ++cc) {
    float4* cur = (cc & 1) ? kb1 : kb0;
    float4* nxt = (cc & 1) ? kb0 : kb1;
    __syncthreads();                 // writes to cur (prev iter / prologue) visible
    float4 g0, g1;
    if (cc + 1 < NCH) {              // issue next chunk's loads; hide under FMAs
      g0 = K4[(size_t)(cc + 1) * 512 + i0];
      g1 = K4[(size_t)(cc + 1) * 512 + i1];
    }
    float4 ka[4], kb[4];
#pragma unroll
    for (int s = 0; s < 4; ++s) {
      ka[s] = cur[lane * 5 + s];
      kb[s] = cur[(lane + 64) * 5 + s];
    }
    float m0 = mp[cc * CK + lane] * -1e9f;
    float m1 = mp[cc * CK + 64 + lane] * -1e9f;
    p0[2 * cc]     = dot16(ka, qa) * 0.25f + m0;
    p0[2 * cc + 1] = dot16(kb, qa) * 0.25f + m1;
    p1[2 * cc]     = dot16(ka, qb) * 0.25f + m0;
    p1[2 * cc + 1] = dot16(kb, qb) * 0.25f + m1;
    if (cc + 1 < NCH) { nxt[s0lds] = g0; nxt[s1lds] = g1; }
  }

  // ---- softmax (wave-wide: 64 lanes x 32 keys = full 2048-key row) ----
  float mx0 = p0[0], mx1 = p1[0];
#pragma unroll
  for (int j = 1; j < 2 * NCH; ++j) { mx0 = fmaxf(mx0, p0[j]); mx1 = fmaxf(mx1, p1[j]); }
#pragma unroll
  for (int m = 1; m < 64; m <<= 1) {
    mx0 = fmaxf(mx0, __shfl_xor(mx0, m));
    mx1 = fmaxf(mx1, __shfl_xor(mx1, m));
  }
  float s0 = 0.f, s1 = 0.f;
#pragma unroll
  for (int j = 0; j < 2 * NCH; ++j) {
    p0[j] = __expf(p0[j] - mx0); s0 += p0[j];
    p1[j] = __expf(p1[j] - mx1); s1 += p1[j];
  }
#pragma unroll
  for (int m = 1; m < 64; m <<= 1) { s0 += __shfl_xor(s0, m); s1 += __shfl_xor(s1, m); }
  const float inv0 = 1.0f / s0, inv1 = 1.0f / s1;

  // ---- write normalized attention (coalesced, non-temporal, from registers) ----
  {
    float* a0 = attn + ((size_t)bh * SEQ + r0) * SEQ;
    float* a1 = a0 + SEQ;
#pragma unroll
    for (int cc = 0; cc < NCH; ++cc) {
      __builtin_nontemporal_store(p0[2 * cc] * inv0,     &a0[cc * CK + lane]);
      __builtin_nontemporal_store(p0[2 * cc + 1] * inv0, &a0[cc * CK + 64 + lane]);
      __builtin_nontemporal_store(p1[2 * cc] * inv1,     &a1[cc * CK + lane]);
      __builtin_nontemporal_store(p1[2 * cc + 1] * inv1, &a1[cc * CK + 64 + lane]);
    }
  }

  // ---- PV (double-buffered) ----
  float4 acc0[4], acc1[4];
#pragma unroll
  for (int s = 0; s < 4; ++s) {
    acc0[s] = make_float4(0.f, 0.f, 0.f, 0.f);
    acc1[s] = make_float4(0.f, 0.f, 0.f, 0.f);
  }
  { // prologue: chunk 0 -> buf0 (safe: all waves past QK iter-15 barrier read buf1)
    float4 g0 = V4[i0], g1 = V4[i1];
    kb0[s0lds] = g0; kb0[s1lds] = g1;
  }
#pragma unroll
  for (int cc = 0; cc < NCH; ++cc) {
    float4* cur = (cc & 1) ? kb1 : kb0;
    float4* nxt = (cc & 1) ? kb0 : kb1;
    __syncthreads();
    float4 g0, g1;
    if (cc + 1 < NCH) {
      g0 = V4[(size_t)(cc + 1) * 512 + i0];
      g1 = V4[(size_t)(cc + 1) * 512 + i1];
    }
    float pa0 = p0[2 * cc], pb0 = p0[2 * cc + 1];
    float pa1 = p1[2 * cc], pb1 = p1[2 * cc + 1];
#pragma unroll
    for (int s = 0; s < 4; ++s) {
      float4 va = cur[lane * 5 + s];
      float4 vb = cur[(lane + 64) * 5 + s];
      acc0[s].x += pa0 * va.x + pb0 * vb.x;
      acc0[s].y += pa0 * va.y + pb0 * vb.y;
      acc0[s].z += pa0 * va.z + pb0 * vb.z;
      acc0[s].w += pa0 * va.w + pb0 * vb.w;
      acc1[s].x += pa1 * va.x + pb1 * vb.x;
      acc1[s].y += pa1 * va.y + pb1 * vb.y;
      acc1[s].z += pa1 * va.z + pb1 * vb.z;
      acc1[s].w += pa1 * va.w + pb1 * vb.w;
    }
    if (cc + 1 < NCH) { nxt[s0lds] = g0; nxt[s1lds] = g1; }
  }
#pragma unroll
  for (int s = 0; s < 4; ++s) {
    acc0[s].x *= inv0; acc0[s].y *= inv0; acc0[s].z *= inv0; acc0[s].w *= inv0;
    acc1[s].x *= inv1; acc1[s].y *= inv1; acc1[s].z *= inv1; acc1[s].w *= inv1;
  }
  // butterfly-reduce ctx partials across the wave
#pragma unroll
  for (int m = 1; m < 64; m <<= 1) {
#pragma unroll
    for (int s = 0; s < 4; ++s) {
      acc0[s].x += __shfl_xor(acc0[s].x, m);
      acc0[s].y += __shfl_xor(acc0[s].y, m);
      acc0[s].z += __shfl_xor(acc0[s].z, m);
      acc0[s].w += __shfl_xor(acc0[s].w, m);
      acc1[s].x += __shfl_xor(acc1[s].x, m);
      acc1[s].y += __shfl_xor(acc1[s].y, m);
      acc1[s].z += __shfl_xor(acc1[s].z, m);
      acc1[s].w += __shfl_xor(acc1[s].w, m);
    }
  }
  if (lane == 0) {
    float4* c4 = (float4*)(ctx + ((size_t)bh * SEQ + r0) * DP);
#pragma unroll
    for (int s = 0; s < 4; ++s) { c4[s] = acc0[s]; c4[4 + s] = acc1[s]; }
  }
}

extern "C" void kernel_launch(void* const* d_in, const int* in_sizes, int n_in,
                              void* d_out, int out_size, void* d_ws, size_t ws_size,
                              hipStream_t stream) {
  const float* q    = (const float*)d_in[0];
  const float* k    = (const float*)d_in[1];
  const float* v    = (const float*)d_in[2];
  const float* mask = (const float*)d_in[3];
  const float* wq_w = (const float*)d_in[4];
  const float* wq_b = (const float*)d_in[5];
  const float* dw   = (const float*)d_in[6];
  const float* db   = (const float*)d_in[7];

  float* ws  = (float*)d_ws;
  float* qh  = ws;                       // [B,H,S,16]
  float* kh  = ws + 1048576;
  float* vh  = ws + 2097152;
  float* ctx = ws + 3145728;             // [B,H,S,16] == flat [8192][128]

  float* out  = (float*)d_out;                     // [4,2048,128]
  float* attn = out + (size_t)BB * SEQ * DM;       // [4,8,2048,2048]

  proj_kernel<<<dim3(128, 3), 256, 0, stream>>>(q, k, v, wq_w, wq_b, ws);
  attn_kernel<<<dim3(8192), 256, 0, stream>>>(qh, kh, vh, mask, attn, ctx);
  dense_kernel<<<dim3(128), 256, 0, stream>>>(ctx, dw, db, out);
}